// Round 2
// baseline (1193.541 us; speedup 1.0000x reference)
//
#include <hip/hip_runtime.h>
#include <math.h>

// Problem constants
#define BB   128
#define SS   1024
#define EH2  1024
#define DHD  512
#define AD   512
#define MTOT (BB*SS)   // 131072
#define KDIM 1024

// k2 tile
#define BM   64
#define BK   32
#define APAD 40        // 32 + 8 halfword pad -> 80B rows: conflict-free b128

typedef __attribute__((ext_vector_type(8))) short  short8;
typedef __attribute__((ext_vector_type(4))) float  f32x4;

static __device__ __forceinline__ unsigned short f2bf_rne(float x) {
    unsigned u = __float_as_uint(x);
    u += 0x7FFF + ((u >> 16) & 1);
    return (unsigned short)(u >> 16);
}

// ---------------------------------------------------------------------------
// k0: repack W_enc (fp32 [K][A]) -> Wt bf16 [K/32][A][32] (k-chunked, rne)
// ---------------------------------------------------------------------------
__global__ __launch_bounds__(256) void k0_wprep(
    const float* __restrict__ W, unsigned short* __restrict__ Wt)
{
    int idx = blockIdx.x * 256 + threadIdx.x;
    for (int i = idx; i < KDIM * AD; i += 512 * 256) {
        int k = i >> 9;        // row in W (K dim)
        int n = i & 511;       // col (A dim)
        Wt[(k >> 5) * (AD * BK) + n * BK + (k & 31)] = f2bf_rne(W[i]);
    }
}

// ---------------------------------------------------------------------------
// k1: dec_proj[b][a] = decoder_hidden[b] @ W_dec + b_attn   (bias folded)
// ---------------------------------------------------------------------------
__global__ __launch_bounds__(256) void k1_decproj(
    const float* __restrict__ dec,   // [B][DH]
    const float* __restrict__ Wdec,  // [DH][A]
    const float* __restrict__ bias,  // [A]
    float* __restrict__ dec_proj)    // [B][A]
{
    __shared__ float dls[DHD];
    const int b = blockIdx.x;
    const int t = threadIdx.x;
    for (int i = t; i < DHD; i += 256) dls[i] = dec[b * DHD + i];
    __syncthreads();
    float acc0 = bias[t];
    float acc1 = bias[t + 256];
    #pragma unroll 8
    for (int k = 0; k < DHD; ++k) {
        const float d = dls[k];
        acc0 += d * Wdec[(size_t)k * AD + t];
        acc1 += d * Wdec[(size_t)k * AD + t + 256];
    }
    dec_proj[b * AD + t]       = acc0;
    dec_proj[b * AD + t + 256] = acc1;
}

// ---------------------------------------------------------------------------
// k2: MFMA GEMM (split-precision bf16x2) + fused tanh + v-dot -> scores.
// Block: 256 thr = 4 waves. Tile: BM=64 rows x full A=512 cols, BK=32.
// Wave w covers cols w*128..w*128+127 (8 n-tiles), all 64 rows (M_rep=4).
// enc is read exactly once (256 KiB/block).
// ---------------------------------------------------------------------------
__global__ __launch_bounds__(256) void k2_gemm_score(
    const float* __restrict__ enc,          // [MTOT][K]
    const unsigned short* __restrict__ Wt,  // [K/32][A][32] bf16
    const float* __restrict__ dp,           // [B][A] (bias folded)
    const float* __restrict__ v,            // [A]
    float* __restrict__ scores)             // [MTOT]
{
    __shared__ unsigned short AsH[BM][APAD];
    __shared__ unsigned short AsL[BM][APAD];
    __shared__ unsigned short Bs[AD][APAD];
    __shared__ float sred[4][BM];

    const int t     = threadIdx.x;
    const int mbase = blockIdx.x * BM;      // never straddles a batch row
    const int b     = blockIdx.x >> 4;      // 64*16 = 1024 = S
    const int wave  = t >> 6;
    const int lane  = t & 63;
    const int ln    = lane & 15;
    const int kgrp  = lane >> 4;            // 0..3
    const int wcol  = wave * 128;

    // A staging coords: thread -> (row, k-chunk of 8)
    const int arow = t >> 2;                // 0..63
    const int akc  = (t & 3) * 8;           // 0,8,16,24

    f32x4 acc[4][8];
    #pragma unroll
    for (int m = 0; m < 4; ++m)
        #pragma unroll
        for (int n = 0; n < 8; ++n) acc[m][n] = (f32x4)0.f;

    const float* encRow = enc + (size_t)(mbase + arow) * KDIM + akc;

    for (int k0 = 0; k0 < KDIM; k0 += BK) {
        __syncthreads();   // previous iter's frag reads done before overwrite

        // ---- A stage: 8 fp32 -> hi (truncate) / lo (rne of remainder)
        const float4 xa = *(const float4*)(encRow + k0);
        const float4 xb = *(const float4*)(encRow + k0 + 4);
        const float xs[8] = {xa.x, xa.y, xa.z, xa.w, xb.x, xb.y, xb.z, xb.w};
        short8 hi, lo;
        #pragma unroll
        for (int j = 0; j < 8; ++j) {
            const unsigned u  = __float_as_uint(xs[j]);
            hi[j] = (short)(u >> 16);
            lo[j] = (short)f2bf_rne(xs[j] - __uint_as_float(u & 0xFFFF0000u));
        }
        *(short8*)&AsH[arow][akc] = hi;
        *(short8*)&AsL[arow][akc] = lo;

        // ---- B stage: 32 KiB contiguous chunk of Wt (L2-resident)
        const unsigned short* wsrc = Wt + (size_t)(k0 >> 5) * (AD * BK);
        #pragma unroll
        for (int r = 0; r < 8; ++r) {
            const int flat = r * 256 + t;        // 0..2047
            const int n  = flat >> 2;
            const int ch = (flat & 3) * 8;
            *(short8*)&Bs[n][ch] = *(const short8*)(wsrc + flat * 8);
        }
        __syncthreads();

        // ---- fragments + MFMA (A row = lane&15, k = 8*(lane>>4)+j)
        short8 afH[4], afL[4];
        #pragma unroll
        for (int m = 0; m < 4; ++m) {
            afH[m] = *(const short8*)&AsH[m * 16 + ln][kgrp * 8];
            afL[m] = *(const short8*)&AsL[m * 16 + ln][kgrp * 8];
        }
        #pragma unroll
        for (int n = 0; n < 8; ++n) {
            const short8 bf = *(const short8*)&Bs[wcol + n * 16 + ln][kgrp * 8];
            #pragma unroll
            for (int m = 0; m < 4; ++m) {
                acc[m][n] = __builtin_amdgcn_mfma_f32_16x16x32_bf16(afH[m], bf, acc[m][n], 0, 0, 0);
                acc[m][n] = __builtin_amdgcn_mfma_f32_16x16x32_bf16(afL[m], bf, acc[m][n], 0, 0, 0);
            }
        }
    }

    // ---- epilogue: score[row] = sum_col v[col]*tanh(acc + dp[col])
    // C/D layout: col = lane&15 (+16n), row = 4*(lane>>4) + i (+16m)
    float dpv[8], vv[8];
    #pragma unroll
    for (int n = 0; n < 8; ++n) {
        const int col = wcol + n * 16 + ln;
        dpv[n] = dp[b * AD + col];
        vv[n]  = v[col];
    }
    #pragma unroll
    for (int m = 0; m < 4; ++m) {
        float s[4];
        #pragma unroll
        for (int i = 0; i < 4; ++i) {
            float sum = 0.f;
            #pragma unroll
            for (int n = 0; n < 8; ++n) {
                const float e  = acc[m][n][i] + dpv[n];
                const float t2 = __expf(2.f * e);          // |e| < ~10: safe
                sum += vv[n] * __fdividef(t2 - 1.f, t2 + 1.f);
            }
            s[i] = sum;
        }
        #pragma unroll
        for (int off = 1; off < 16; off <<= 1) {
            #pragma unroll
            for (int i = 0; i < 4; ++i) s[i] += __shfl_xor(s[i], off);
        }
        if (ln == 0) {
            f32x4 sv = {s[0], s[1], s[2], s[3]};
            *(f32x4*)&sred[wave][m * 16 + kgrp * 4] = sv;   // rows of this m-tile
        }
    }
    __syncthreads();
    if (t < BM)
        scores[mbase + t] = sred[0][t] + sred[1][t] + sred[2][t] + sred[3][t];
}

// ---------------------------------------------------------------------------
// k3: mask + softmax over S
// ---------------------------------------------------------------------------
__global__ __launch_bounds__(256) void k3_softmax(
    const float* __restrict__ sc,    // [MTOT]
    const int*   __restrict__ mask,  // [B][S]
    float* __restrict__ wts)         // [B][S]
{
    const int b = blockIdx.x;
    const int t = threadIdx.x;
    float local[4];
    float mx = -3.0e38f;
    #pragma unroll
    for (int r = 0; r < 4; ++r) {
        const int s = r * 256 + t;
        float val = sc[b * SS + s];
        if (mask[b * SS + s] == 0) val = -1.0e10f;
        local[r] = val;
        mx = fmaxf(mx, val);
    }
    #pragma unroll
    for (int off = 1; off < 64; off <<= 1) mx = fmaxf(mx, __shfl_xor(mx, off));
    __shared__ float redm[4], reds[4];
    if ((t & 63) == 0) redm[t >> 6] = mx;
    __syncthreads();
    mx = fmaxf(fmaxf(redm[0], redm[1]), fmaxf(redm[2], redm[3]));

    float sum = 0.f;
    #pragma unroll
    for (int r = 0; r < 4; ++r) { local[r] = __expf(local[r] - mx); sum += local[r]; }
    #pragma unroll
    for (int off = 1; off < 64; off <<= 1) sum += __shfl_xor(sum, off);
    if ((t & 63) == 0) reds[t >> 6] = sum;
    __syncthreads();
    sum = reds[0] + reds[1] + reds[2] + reds[3];
    const float inv = 1.f / sum;
    #pragma unroll
    for (int r = 0; r < 4; ++r) wts[b * SS + r * 256 + t] = local[r] * inv;
}

// ---------------------------------------------------------------------------
// k4: context[b][e] = sum_s w[b][s] * enc[b][s][e]
// ---------------------------------------------------------------------------
#define SCHUNK 128
__global__ __launch_bounds__(256) void k4_context(
    const float* __restrict__ enc,   // [B][S][E]
    const float* __restrict__ wts,   // [B][S]
    float* __restrict__ ctx)         // [B][E], pre-zeroed
{
    const int b  = blockIdx.x;
    const int ch = blockIdx.y;
    const int e4 = threadIdx.x * 4;
    const float* encb = enc + (size_t)b * SS * EH2 + (size_t)ch * SCHUNK * EH2;
    const float* wb   = wts + b * SS + ch * SCHUNK;
    float4 acc = make_float4(0.f, 0.f, 0.f, 0.f);
    #pragma unroll 4
    for (int s = 0; s < SCHUNK; ++s) {
        const float w = wb[s];
        const float4 ev = *(const float4*)&encb[(size_t)s * EH2 + e4];
        acc.x = fmaf(w, ev.x, acc.x);
        acc.y = fmaf(w, ev.y, acc.y);
        acc.z = fmaf(w, ev.z, acc.z);
        acc.w = fmaf(w, ev.w, acc.w);
    }
    atomicAdd(&ctx[b * EH2 + e4 + 0], acc.x);
    atomicAdd(&ctx[b * EH2 + e4 + 1], acc.y);
    atomicAdd(&ctx[b * EH2 + e4 + 2], acc.z);
    atomicAdd(&ctx[b * EH2 + e4 + 3], acc.w);
}

// ---------------------------------------------------------------------------
extern "C" void kernel_launch(void* const* d_in, const int* in_sizes, int n_in,
                              void* d_out, int out_size, void* d_ws, size_t ws_size,
                              hipStream_t stream) {
    const float* enc    = (const float*)d_in[0];   // (B,S,EH2)
    const float* dec    = (const float*)d_in[1];   // (B,DH)
    const int*   mask   = (const int*)  d_in[2];   // (B,S)
    const float* W      = (const float*)d_in[3];   // (EH2+DH, A)
    const float* b_attn = (const float*)d_in[4];   // (A,)
    const float* v      = (const float*)d_in[5];   // (A,)

    float* out = (float*)d_out;
    float* ctx = out;                // B*EH2
    float* wts = out + BB * EH2;     // B*S

    unsigned short* Wt  = (unsigned short*)d_ws;                    // 1 MiB
    float* dec_proj     = (float*)((char*)d_ws + (1 << 20));        // 256 KiB
    float* scores       = dec_proj + BB * AD;                       // 512 KiB

    hipMemsetAsync(ctx, 0, (size_t)BB * EH2 * sizeof(float), stream);

    k0_wprep<<<512, 256, 0, stream>>>(W, Wt);

    k1_decproj<<<BB, 256, 0, stream>>>(dec, W + (size_t)EH2 * AD, b_attn, dec_proj);

    k2_gemm_score<<<MTOT / BM, 256, 0, stream>>>(enc, Wt, dec_proj, v, scores);

    k3_softmax<<<BB, 256, 0, stream>>>(scores, mask, wts);

    dim3 g4(BB, SS / SCHUNK);        // (128, 8)
    k4_context<<<g4, 256, 0, stream>>>(enc, wts, ctx);
}

// Round 3
// 1035.602 us; speedup vs baseline: 1.1525x; 1.1525x over previous
//
#include <hip/hip_runtime.h>
#include <math.h>

// Problem constants
#define BB   128
#define SS   1024
#define EH2  1024
#define DHD  512
#define AD   512
#define MTOT (BB*SS)   // 131072
#define KDIM 1024

// k2 tile
#define BM2   128          // rows per block
#define BK2   32           // K per step
#define NSTEP (KDIM/BK2)   // 32

typedef __attribute__((ext_vector_type(8)))  short short8;
typedef __attribute__((ext_vector_type(4)))  float f32x4;
typedef __attribute__((ext_vector_type(16))) float f32x16;

static __device__ __forceinline__ unsigned short f2bf_rne(float x) {
    unsigned u = __float_as_uint(x);
    u += 0x7FFF + ((u >> 16) & 1);
    return (unsigned short)(u >> 16);
}

#define LDS_AS(p) ((__attribute__((address_space(3))) unsigned int*)(p))
#define GLB_AS(p) ((const __attribute__((address_space(1))) unsigned int*)(p))

// ---------------------------------------------------------------------------
// k0: pack W_enc fp32 [K][A] -> Wt bf16 in MFMA-fragment order:
// Wt[ks][kk2][ct][lane][j]  (ks=K32 step, kk2=K16 half, ct=col tile of 32)
//   element = W[ks*32 + kk2*16 + (lane>>5)*8 + j][ct*32 + (lane&31)]
// Writes are 16 B/lane coalesced.
// ---------------------------------------------------------------------------
__global__ __launch_bounds__(256) void k0_wprep(
    const float* __restrict__ W, unsigned short* __restrict__ Wt)
{
    const int g     = blockIdx.x * 256 + threadIdx.x;  // 0..65535
    const int lane  = g & 63;
    const int ct    = (g >> 6) & 15;
    const int kk2   = (g >> 10) & 1;
    const int ks    = g >> 11;                          // 0..31
    const int col   = ct * 32 + (lane & 31);
    const int kbase = ks * 32 + kk2 * 16 + (lane >> 5) * 8;
    short8 out;
    #pragma unroll
    for (int j = 0; j < 8; ++j)
        out[j] = (short)f2bf_rne(W[(size_t)(kbase + j) * AD + col]);
    *(short8*)&Wt[(size_t)g * 8] = out;
}

// ---------------------------------------------------------------------------
// k1: dec_proj[b][a] = decoder_hidden[b] @ W_dec + b_attn   (bias folded)
// ---------------------------------------------------------------------------
__global__ __launch_bounds__(256) void k1_decproj(
    const float* __restrict__ dec,   // [B][DH]
    const float* __restrict__ Wdec,  // [DH][A]
    const float* __restrict__ bias,  // [A]
    float* __restrict__ dec_proj)    // [B][A]
{
    __shared__ float dls[DHD];
    const int b = blockIdx.x;
    const int t = threadIdx.x;
    for (int i = t; i < DHD; i += 256) dls[i] = dec[b * DHD + i];
    __syncthreads();
    float acc0 = bias[t];
    float acc1 = bias[t + 256];
    #pragma unroll 8
    for (int k = 0; k < DHD; ++k) {
        const float d = dls[k];
        acc0 += d * Wdec[(size_t)k * AD + t];
        acc1 += d * Wdec[(size_t)k * AD + t + 256];
    }
    dec_proj[b * AD + t]       = acc0;
    dec_proj[b * AD + t + 256] = acc1;
}

// ---------------------------------------------------------------------------
// k2: MFMA GEMM (split bf16 hi/lo) + fused tanh + v-dot -> scores[MTOT].
// 512 thr = 8 waves (2m x 4n). Block tile 128 rows x 512 cols, BK=32.
// MFMA 32x32x16_bf16; wave tile 64x128 (acc[2][4] x f32x16 = 128 AGPR).
// All LDS accesses fragment-linear (lane*16 B): zero bank conflicts.
// Double-buffered: B via global_load_lds, A via reg-stage (T14 split).
// ---------------------------------------------------------------------------
__global__ __launch_bounds__(512, 2) void k2_gemm_score(
    const float* __restrict__ enc,          // [MTOT][K]
    const unsigned short* __restrict__ Wt,  // packed fragment order
    const float* __restrict__ dp,           // [B][A] (bias folded)
    const float* __restrict__ v,            // [A]
    float* __restrict__ scores)             // [MTOT]
{
    // chunk = 512 halfwords = one 64-lane fragment group (1 KB)
    __shared__ unsigned short As[2][16][512]; // [(hl*2+kk2)*4+mt][lane*8+j] 16 KB/buf
    __shared__ unsigned short Bs[2][32][512]; // [kk2*16+ct][lane*8+j]      32 KB/buf
    __shared__ float dp_l[AD], v_l[AD];
    __shared__ float sred[4][BM2];

    const int t     = threadIdx.x;
    const int wave  = t >> 6;
    const int lane  = t & 63;
    const int mbase = blockIdx.x * BM2;
    const int b     = blockIdx.x >> 3;      // 8 blocks per batch row
    const int wm    = wave >> 2;            // 0..1
    const int wn    = wave & 3;             // 0..3

    dp_l[t] = dp[b * AD + t];
    v_l[t]  = v[t];

    // A-staging task: thread -> (mt, kk2, lane) fragment slot (8 fp32 = 32 B)
    const int smt   = (t >> 6) & 3;
    const int skk2  = t >> 8;
    const int srow  = smt * 32 + (lane & 31);
    const int sksub = skk2 * 16 + (lane >> 5) * 8;
    const float* aptr = enc + (size_t)(mbase + srow) * KDIM + sksub;
    unsigned short* asH = &As[0][skk2 * 4 + smt][lane * 8];        // hl=0
    unsigned short* asL = &As[0][(2 + skk2) * 4 + smt][lane * 8];  // hl=1
    const int asStride = 16 * 512;  // halfwords per As buffer

    // B-staging: wave copies 4 KB/step, 16 B/lane, fragment-linear
    const unsigned short* bsrc = Wt + (size_t)wave * 2048 + (size_t)lane * 8;
    unsigned short* bdst = &Bs[0][wave * 4][0];
    const int bsStride = 32 * 512;

#define STAGE_B(ks_, buf_) do {                                             \
    const unsigned short* gs_ = bsrc + (size_t)(ks_) * 16384;               \
    unsigned short* ds_ = bdst + (buf_) * bsStride;                         \
    __builtin_amdgcn_global_load_lds(GLB_AS(gs_),        LDS_AS(ds_),        16, 0, 0); \
    __builtin_amdgcn_global_load_lds(GLB_AS(gs_ + 512),  LDS_AS(ds_ + 512),  16, 0, 0); \
    __builtin_amdgcn_global_load_lds(GLB_AS(gs_ + 1024), LDS_AS(ds_ + 1024), 16, 0, 0); \
    __builtin_amdgcn_global_load_lds(GLB_AS(gs_ + 1536), LDS_AS(ds_ + 1536), 16, 0, 0); \
} while (0)

#define CONV_WRITE_A(buf_, xa_, xb_) do {                                   \
    const float xs_[8] = {xa_.x, xa_.y, xa_.z, xa_.w, xb_.x, xb_.y, xb_.z, xb_.w}; \
    short8 hi_, lo_;                                                        \
    _Pragma("unroll")                                                       \
    for (int j_ = 0; j_ < 8; ++j_) {                                        \
        const unsigned u_ = __float_as_uint(xs_[j_]);                       \
        hi_[j_] = (short)(u_ >> 16);                                        \
        lo_[j_] = (short)f2bf_rne(xs_[j_] - __uint_as_float(u_ & 0xFFFF0000u)); \
    }                                                                       \
    *(short8*)(asH + (buf_) * asStride) = hi_;                              \
    *(short8*)(asL + (buf_) * asStride) = lo_;                              \
} while (0)

    f32x16 acc[2][4];
    #pragma unroll
    for (int mi = 0; mi < 2; ++mi)
        #pragma unroll
        for (int n = 0; n < 4; ++n) acc[mi][n] = (f32x16)0.f;

    // prologue: stage step 0 into buf 0
    STAGE_B(0, 0);
    {
        const float4 xa = *(const float4*)(aptr);
        const float4 xb = *(const float4*)(aptr + 4);
        CONV_WRITE_A(0, xa, xb);
    }
    __syncthreads();

    int cur = 0;
    for (int ks = 0; ks < NSTEP; ++ks) {
        const int nxt = cur ^ 1;
        float4 xa, xb;
        const bool pf = (ks + 1 < NSTEP);
        if (pf) {
            STAGE_B(ks + 1, nxt);                        // latency hidden under MFMA
            xa = *(const float4*)(aptr + (ks + 1) * BK2);
            xb = *(const float4*)(aptr + (ks + 1) * BK2 + 4);
        }

        #pragma unroll
        for (int kk2 = 0; kk2 < 2; ++kk2) {
            short8 bf[4];
            #pragma unroll
            for (int n = 0; n < 4; ++n)
                bf[n] = *(const short8*)&Bs[cur][kk2 * 16 + wn * 4 + n][lane * 8];
            #pragma unroll
            for (int mi = 0; mi < 2; ++mi) {
                const int mt = wm * 2 + mi;
                const short8 aH = *(const short8*)&As[cur][kk2 * 4 + mt][lane * 8];
                const short8 aL = *(const short8*)&As[cur][(2 + kk2) * 4 + mt][lane * 8];
                #pragma unroll
                for (int n = 0; n < 4; ++n) {
                    acc[mi][n] = __builtin_amdgcn_mfma_f32_32x32x16_bf16(aH, bf[n], acc[mi][n], 0, 0, 0);
                    acc[mi][n] = __builtin_amdgcn_mfma_f32_32x32x16_bf16(aL, bf[n], acc[mi][n], 0, 0, 0);
                }
            }
        }

        if (pf) CONV_WRITE_A(nxt, xa, xb);
        __syncthreads();
        cur = nxt;
    }

    // ---- epilogue: score[row] = sum_col v[col]*tanh(acc + dp[col])
    // 32x32 C/D: col = lane&31, row = 4*(lane>>5) + (r&3) + 8*(r>>2)
    const int c    = lane & 31;
    const int half = lane >> 5;
    float vv[4], dpv[4];
    #pragma unroll
    for (int n = 0; n < 4; ++n) {
        const int col = wn * 128 + n * 32 + c;
        vv[n]  = v_l[col];
        dpv[n] = dp_l[col];
    }
    #pragma unroll
    for (int mi = 0; mi < 2; ++mi) {
        const int mt = wm * 2 + mi;
        float part[16];
        #pragma unroll
        for (int r = 0; r < 16; ++r) {
            float s = 0.f;
            #pragma unroll
            for (int n = 0; n < 4; ++n) {
                const float e  = acc[mi][n][r] + dpv[n];
                const float te = __expf(2.f * e);
                s += vv[n] * (1.f - __fdividef(2.f, te + 1.f));
            }
            part[r] = s;
        }
        #pragma unroll
        for (int off = 1; off < 32; off <<= 1)
            #pragma unroll
            for (int r = 0; r < 16; ++r)
                part[r] += __shfl_xor(part[r], off);
        if (c == 0) {
            #pragma unroll
            for (int r = 0; r < 16; ++r)
                sred[wn][mt * 32 + 4 * half + (r & 3) + 8 * (r >> 2)] = part[r];
        }
    }
    __syncthreads();
    if (t < BM2)
        scores[mbase + t] = sred[0][t] + sred[1][t] + sred[2][t] + sred[3][t];
#undef STAGE_B
#undef CONV_WRITE_A
}

// ---------------------------------------------------------------------------
// k3: mask + softmax over S
// ---------------------------------------------------------------------------
__global__ __launch_bounds__(256) void k3_softmax(
    const float* __restrict__ sc,    // [MTOT]
    const int*   __restrict__ mask,  // [B][S]
    float* __restrict__ wts)         // [B][S]
{
    const int b = blockIdx.x;
    const int t = threadIdx.x;
    float local[4];
    float mx = -3.0e38f;
    #pragma unroll
    for (int r = 0; r < 4; ++r) {
        const int s = r * 256 + t;
        float val = sc[b * SS + s];
        if (mask[b * SS + s] == 0) val = -1.0e10f;
        local[r] = val;
        mx = fmaxf(mx, val);
    }
    #pragma unroll
    for (int off = 1; off < 64; off <<= 1) mx = fmaxf(mx, __shfl_xor(mx, off));
    __shared__ float redm[4], reds[4];
    if ((t & 63) == 0) redm[t >> 6] = mx;
    __syncthreads();
    mx = fmaxf(fmaxf(redm[0], redm[1]), fmaxf(redm[2], redm[3]));

    float sum = 0.f;
    #pragma unroll
    for (int r = 0; r < 4; ++r) { local[r] = __expf(local[r] - mx); sum += local[r]; }
    #pragma unroll
    for (int off = 1; off < 64; off <<= 1) sum += __shfl_xor(sum, off);
    if ((t & 63) == 0) reds[t >> 6] = sum;
    __syncthreads();
    sum = reds[0] + reds[1] + reds[2] + reds[3];
    const float inv = 1.f / sum;
    #pragma unroll
    for (int r = 0; r < 4; ++r) wts[b * SS + r * 256 + t] = local[r] * inv;
}

// ---------------------------------------------------------------------------
// k4: context[b][e] = sum_s w[b][s] * enc[b][s][e]
// ---------------------------------------------------------------------------
#define SCHUNK 128
__global__ __launch_bounds__(256) void k4_context(
    const float* __restrict__ enc,   // [B][S][E]
    const float* __restrict__ wts,   // [B][S]
    float* __restrict__ ctx)         // [B][E], pre-zeroed
{
    const int b  = blockIdx.x;
    const int ch = blockIdx.y;
    const int e4 = threadIdx.x * 4;
    const float* encb = enc + (size_t)b * SS * EH2 + (size_t)ch * SCHUNK * EH2;
    const float* wb   = wts + b * SS + ch * SCHUNK;
    float4 acc = make_float4(0.f, 0.f, 0.f, 0.f);
    #pragma unroll 4
    for (int s = 0; s < SCHUNK; ++s) {
        const float w = wb[s];
        const float4 ev = *(const float4*)&encb[(size_t)s * EH2 + e4];
        acc.x = fmaf(w, ev.x, acc.x);
        acc.y = fmaf(w, ev.y, acc.y);
        acc.z = fmaf(w, ev.z, acc.z);
        acc.w = fmaf(w, ev.w, acc.w);
    }
    atomicAdd(&ctx[b * EH2 + e4 + 0], acc.x);
    atomicAdd(&ctx[b * EH2 + e4 + 1], acc.y);
    atomicAdd(&ctx[b * EH2 + e4 + 2], acc.z);
    atomicAdd(&ctx[b * EH2 + e4 + 3], acc.w);
}

// ---------------------------------------------------------------------------
extern "C" void kernel_launch(void* const* d_in, const int* in_sizes, int n_in,
                              void* d_out, int out_size, void* d_ws, size_t ws_size,
                              hipStream_t stream) {
    const float* enc    = (const float*)d_in[0];   // (B,S,EH2)
    const float* dec    = (const float*)d_in[1];   // (B,DH)
    const int*   mask   = (const int*)  d_in[2];   // (B,S)
    const float* W      = (const float*)d_in[3];   // (EH2+DH, A)
    const float* b_attn = (const float*)d_in[4];   // (A,)
    const float* v      = (const float*)d_in[5];   // (A,)

    float* out = (float*)d_out;
    float* ctx = out;                // B*EH2
    float* wts = out + BB * EH2;     // B*S

    unsigned short* Wt  = (unsigned short*)d_ws;                    // 1 MiB
    float* dec_proj     = (float*)((char*)d_ws + (1 << 20));        // 256 KiB
    float* scores       = dec_proj + BB * AD;                       // 512 KiB

    hipMemsetAsync(ctx, 0, (size_t)BB * EH2 * sizeof(float), stream);

    k0_wprep<<<256, 256, 0, stream>>>(W, Wt);

    k1_decproj<<<BB, 256, 0, stream>>>(dec, W + (size_t)EH2 * AD, b_attn, dec_proj);

    k2_gemm_score<<<MTOT / BM2, 512, 0, stream>>>(enc, Wt, dec_proj, v, scores);

    k3_softmax<<<BB, 256, 0, stream>>>(scores, mask, wts);

    dim3 g4(BB, SS / SCHUNK);        // (128, 8)
    k4_context<<<g4, 256, 0, stream>>>(enc, wts, ctx);
}

// Round 4
// 1027.607 us; speedup vs baseline: 1.1615x; 1.0078x over previous
//
#include <hip/hip_runtime.h>
#include <math.h>

// Problem constants
#define BB   128
#define SS   1024
#define EH2  1024
#define DHD  512
#define AD   512
#define MTOT (BB*SS)   // 131072
#define KDIM 1024

// k2 tile: block = 256 thr (4 waves), tile 64 rows x 512 cols, BK=32
#define BM2   64
#define BK2   32
#define NSTEP (KDIM/BK2)   // 32

typedef __attribute__((ext_vector_type(8)))  short short8;
typedef __attribute__((ext_vector_type(16))) float f32x16;

static __device__ __forceinline__ unsigned short f2bf_rne(float x) {
    unsigned u = __float_as_uint(x);
    u += 0x7FFF + ((u >> 16) & 1);
    return (unsigned short)(u >> 16);
}

// ---------------------------------------------------------------------------
// k0: pack W_enc fp32 [K][A] -> Wt bf16 in MFMA-fragment order:
//   Wt[ks][kk2][ct][lane][j] = W[ks*32 + kk2*16 + (lane>>5)*8 + j][ct*32 + (lane&31)]
// ---------------------------------------------------------------------------
__global__ __launch_bounds__(256) void k0_wprep(
    const float* __restrict__ W, unsigned short* __restrict__ Wt)
{
    const int g     = blockIdx.x * 256 + threadIdx.x;  // 0..65535
    const int lane  = g & 63;
    const int ct    = (g >> 6) & 15;
    const int kk2   = (g >> 10) & 1;
    const int ks    = g >> 11;                          // 0..31
    const int col   = ct * 32 + (lane & 31);
    const int kbase = ks * 32 + kk2 * 16 + (lane >> 5) * 8;
    short8 out;
    #pragma unroll
    for (int j = 0; j < 8; ++j)
        out[j] = (short)f2bf_rne(W[(size_t)(kbase + j) * AD + col]);
    *(short8*)&Wt[(size_t)g * 8] = out;
}

// ---------------------------------------------------------------------------
// k1: dec_proj[b][a] = decoder_hidden[b] @ W_dec + b_attn   (bias folded)
// ---------------------------------------------------------------------------
__global__ __launch_bounds__(256) void k1_decproj(
    const float* __restrict__ dec,   // [B][DH]
    const float* __restrict__ Wdec,  // [DH][A]
    const float* __restrict__ bias,  // [A]
    float* __restrict__ dec_proj)    // [B][A]
{
    __shared__ float dls[DHD];
    const int b = blockIdx.x;
    const int t = threadIdx.x;
    for (int i = t; i < DHD; i += 256) dls[i] = dec[b * DHD + i];
    __syncthreads();
    float acc0 = bias[t];
    float acc1 = bias[t + 256];
    #pragma unroll 8
    for (int k = 0; k < DHD; ++k) {
        const float d = dls[k];
        acc0 += d * Wdec[(size_t)k * AD + t];
        acc1 += d * Wdec[(size_t)k * AD + t + 256];
    }
    dec_proj[b * AD + t]       = acc0;
    dec_proj[b * AD + t + 256] = acc1;
}

// ---------------------------------------------------------------------------
// k2: MFMA GEMM (split bf16 hi/lo) + fused tanh + v-dot -> scores[MTOT].
// 256 thr = 4 waves (1m x 4n). Block tile 64 x 512, BK=32.
// B-frags: global->reg direct from fragment-ordered Wt (L2-resident, no LDS).
// A: LDS double-buffered hi/lo, fragment-linear (zero bank conflicts).
// Two blocks co-resident per CU -> independent barrier groups overlap.
// ---------------------------------------------------------------------------
#define AS_IDX(hl, kk2, mt) (((hl) * 2 + (kk2)) * 2 + (mt))

__global__ __launch_bounds__(256, 2) void k2_gemm_score(
    const float* __restrict__ enc,          // [MTOT][K]
    const unsigned short* __restrict__ Wt,  // packed fragment order
    const float* __restrict__ dp,           // [B][A] (bias folded)
    const float* __restrict__ v,            // [A]
    float* __restrict__ scores)             // [MTOT]
{
    __shared__ unsigned short As[2][8][512];   // 16 KB: [buf][AS_IDX][lane*8+j]
    __shared__ float dp_l[AD], v_l[AD];
    __shared__ float sred[4][BM2];

    const int t     = threadIdx.x;
    const int wn    = t >> 6;               // wave = n-quadrant
    const int lane  = t & 63;
    const int mbase = blockIdx.x * BM2;
    const int b     = blockIdx.x >> 4;      // 16 blocks per batch row

    dp_l[t]       = dp[b * AD + t];
    dp_l[t + 256] = dp[b * AD + t + 256];
    v_l[t]        = v[t];
    v_l[t + 256]  = v[t + 256];

    // A staging task: (smt, skk2, lane) fragment slot, 8 fp32 each
    const int smt  = (t >> 6) & 1;
    const int skk2 = t >> 7;
    const int srow = smt * 32 + (lane & 31);
    const int skb  = skk2 * 16 + (lane >> 5) * 8;
    const float* aptr = enc + (size_t)(mbase + srow) * KDIM + skb;
    unsigned short* asH = &As[0][AS_IDX(0, skk2, smt)][lane * 8];
    unsigned short* asL = &As[0][AS_IDX(1, skk2, smt)][lane * 8];
    const int asStride = 8 * 512;   // halfwords per As buffer

    // B fragment base: short8 units
    const short8* bbase = (const short8*)Wt + wn * 256 + lane;

#define CONV_WRITE_A(buf_, xa_, xb_) do {                                   \
    const float xs_[8] = {xa_.x, xa_.y, xa_.z, xa_.w, xb_.x, xb_.y, xb_.z, xb_.w}; \
    short8 hi_, lo_;                                                        \
    _Pragma("unroll")                                                       \
    for (int j_ = 0; j_ < 8; ++j_) {                                        \
        const unsigned u_ = __float_as_uint(xs_[j_]);                       \
        hi_[j_] = (short)(u_ >> 16);                                        \
        lo_[j_] = (short)f2bf_rne(xs_[j_] - __uint_as_float(u_ & 0xFFFF0000u)); \
    }                                                                       \
    *(short8*)(asH + (buf_) * asStride) = hi_;                              \
    *(short8*)(asL + (buf_) * asStride) = lo_;                              \
} while (0)

    f32x16 acc[2][4];
    #pragma unroll
    for (int mi = 0; mi < 2; ++mi)
        #pragma unroll
        for (int n = 0; n < 4; ++n) acc[mi][n] = (f32x16)0.f;

    // prologue: stage ks=0 into buf0
    {
        const float4 xa = *(const float4*)(aptr);
        const float4 xb = *(const float4*)(aptr + 4);
        CONV_WRITE_A(0, xa, xb);
    }
    __syncthreads();

// One K-step with compile-time buffer index BUF (reads BUF, stages BUF^1).
#define KSTEP(BUF, ks_)                                                      \
  {                                                                          \
    const bool pf = ((ks_) + 1 < NSTEP);                                     \
    float4 xa, xb;                                                           \
    if (pf) {                                                                \
        xa = *(const float4*)(aptr + ((ks_) + 1) * BK2);                     \
        xb = *(const float4*)(aptr + ((ks_) + 1) * BK2 + 4);                 \
    }                                                                        \
    /* kk2 = 0 */                                                            \
    {                                                                        \
        short8 bfr[4];                                                       \
        _Pragma("unroll")                                                    \
        for (int n = 0; n < 4; ++n) bfr[n] = bbase[(ks_) * 2048 + n * 64];   \
        const short8 aH0 = *(const short8*)&As[BUF][AS_IDX(0,0,0)][lane*8];  \
        const short8 aL0 = *(const short8*)&As[BUF][AS_IDX(1,0,0)][lane*8];  \
        const short8 aH1 = *(const short8*)&As[BUF][AS_IDX(0,0,1)][lane*8];  \
        const short8 aL1 = *(const short8*)&As[BUF][AS_IDX(1,0,1)][lane*8];  \
        __builtin_amdgcn_s_setprio(1);                                       \
        _Pragma("unroll")                                                    \
        for (int n = 0; n < 4; ++n) {                                        \
            acc[0][n] = __builtin_amdgcn_mfma_f32_32x32x16_bf16(aH0, bfr[n], acc[0][n], 0, 0, 0); \
            acc[0][n] = __builtin_amdgcn_mfma_f32_32x32x16_bf16(aL0, bfr[n], acc[0][n], 0, 0, 0); \
            acc[1][n] = __builtin_amdgcn_mfma_f32_32x32x16_bf16(aH1, bfr[n], acc[1][n], 0, 0, 0); \
            acc[1][n] = __builtin_amdgcn_mfma_f32_32x32x16_bf16(aL1, bfr[n], acc[1][n], 0, 0, 0); \
        }                                                                    \
        __builtin_amdgcn_s_setprio(0);                                       \
    }                                                                        \
    /* kk2 = 1 */                                                            \
    {                                                                        \
        short8 bfr[4];                                                       \
        _Pragma("unroll")                                                    \
        for (int n = 0; n < 4; ++n) bfr[n] = bbase[(ks_) * 2048 + 1024 + n * 64]; \
        const short8 aH0 = *(const short8*)&As[BUF][AS_IDX(0,1,0)][lane*8];  \
        const short8 aL0 = *(const short8*)&As[BUF][AS_IDX(1,1,0)][lane*8];  \
        const short8 aH1 = *(const short8*)&As[BUF][AS_IDX(0,1,1)][lane*8];  \
        const short8 aL1 = *(const short8*)&As[BUF][AS_IDX(1,1,1)][lane*8];  \
        __builtin_amdgcn_s_setprio(1);                                       \
        _Pragma("unroll")                                                    \
        for (int n = 0; n < 4; ++n) {                                        \
            acc[0][n] = __builtin_amdgcn_mfma_f32_32x32x16_bf16(aH0, bfr[n], acc[0][n], 0, 0, 0); \
            acc[0][n] = __builtin_amdgcn_mfma_f32_32x32x16_bf16(aL0, bfr[n], acc[0][n], 0, 0, 0); \
            acc[1][n] = __builtin_amdgcn_mfma_f32_32x32x16_bf16(aH1, bfr[n], acc[1][n], 0, 0, 0); \
            acc[1][n] = __builtin_amdgcn_mfma_f32_32x32x16_bf16(aL1, bfr[n], acc[1][n], 0, 0, 0); \
        }                                                                    \
        __builtin_amdgcn_s_setprio(0);                                       \
    }                                                                        \
    if (pf) CONV_WRITE_A((BUF) ^ 1, xa, xb);                                 \
    __syncthreads();                                                         \
  }

    for (int ks = 0; ks < NSTEP; ks += 2) {
        KSTEP(0, ks);
        KSTEP(1, ks + 1);
    }
#undef KSTEP
#undef CONV_WRITE_A

    // ---- epilogue: score[row] = sum_col v[col]*tanh(acc + dp[col])
    // 32x32 C/D: col = lane&31, row = 4*(lane>>5) + (r&3) + 8*(r>>2)
    const int c    = lane & 31;
    const int half = lane >> 5;
    float vv[4], dpv[4];
    #pragma unroll
    for (int n = 0; n < 4; ++n) {
        const int col = wn * 128 + n * 32 + c;
        vv[n]  = v_l[col];
        dpv[n] = dp_l[col];
    }
    #pragma unroll
    for (int mi = 0; mi < 2; ++mi) {
        float part[16];
        #pragma unroll
        for (int r = 0; r < 16; ++r) {
            float s = 0.f;
            #pragma unroll
            for (int n = 0; n < 4; ++n) {
                const float e  = acc[mi][n][r] + dpv[n];
                const float te = __expf(2.f * e);
                s += vv[n] * (1.f - __fdividef(2.f, te + 1.f));
            }
            part[r] = s;
        }
        #pragma unroll
        for (int off = 1; off < 32; off <<= 1)
            #pragma unroll
            for (int r = 0; r < 16; ++r)
                part[r] += __shfl_xor(part[r], off);
        if (c == 0) {
            #pragma unroll
            for (int r = 0; r < 16; ++r)
                sred[wn][mi * 32 + 4 * half + (r & 3) + 8 * (r >> 2)] = part[r];
        }
    }
    __syncthreads();
    if (t < BM2)
        scores[mbase + t] = sred[0][t] + sred[1][t] + sred[2][t] + sred[3][t];
}

// ---------------------------------------------------------------------------
// k3: mask + softmax over S
// ---------------------------------------------------------------------------
__global__ __launch_bounds__(256) void k3_softmax(
    const float* __restrict__ sc,    // [MTOT]
    const int*   __restrict__ mask,  // [B][S]
    float* __restrict__ wts)         // [B][S]
{
    const int b = blockIdx.x;
    const int t = threadIdx.x;
    float local[4];
    float mx = -3.0e38f;
    #pragma unroll
    for (int r = 0; r < 4; ++r) {
        const int s = r * 256 + t;
        float val = sc[b * SS + s];
        if (mask[b * SS + s] == 0) val = -1.0e10f;
        local[r] = val;
        mx = fmaxf(mx, val);
    }
    #pragma unroll
    for (int off = 1; off < 64; off <<= 1) mx = fmaxf(mx, __shfl_xor(mx, off));
    __shared__ float redm[4], reds[4];
    if ((t & 63) == 0) redm[t >> 6] = mx;
    __syncthreads();
    mx = fmaxf(fmaxf(redm[0], redm[1]), fmaxf(redm[2], redm[3]));

    float sum = 0.f;
    #pragma unroll
    for (int r = 0; r < 4; ++r) { local[r] = __expf(local[r] - mx); sum += local[r]; }
    #pragma unroll
    for (int off = 1; off < 64; off <<= 1) sum += __shfl_xor(sum, off);
    if ((t & 63) == 0) reds[t >> 6] = sum;
    __syncthreads();
    sum = reds[0] + reds[1] + reds[2] + reds[3];
    const float inv = 1.f / sum;
    #pragma unroll
    for (int r = 0; r < 4; ++r) wts[b * SS + r * 256 + t] = local[r] * inv;
}

// ---------------------------------------------------------------------------
// k4: context[b][e] = sum_s w[b][s] * enc[b][s][e]
// ---------------------------------------------------------------------------
#define SCHUNK 128
__global__ __launch_bounds__(256) void k4_context(
    const float* __restrict__ enc,   // [B][S][E]
    const float* __restrict__ wts,   // [B][S]
    float* __restrict__ ctx)         // [B][E], pre-zeroed
{
    const int b  = blockIdx.x;
    const int ch = blockIdx.y;
    const int e4 = threadIdx.x * 4;
    const float* encb = enc + (size_t)b * SS * EH2 + (size_t)ch * SCHUNK * EH2;
    const float* wb   = wts + b * SS + ch * SCHUNK;
    float4 acc = make_float4(0.f, 0.f, 0.f, 0.f);
    #pragma unroll 4
    for (int s = 0; s < SCHUNK; ++s) {
        const float w = wb[s];
        const float4 ev = *(const float4*)&encb[(size_t)s * EH2 + e4];
        acc.x = fmaf(w, ev.x, acc.x);
        acc.y = fmaf(w, ev.y, acc.y);
        acc.z = fmaf(w, ev.z, acc.z);
        acc.w = fmaf(w, ev.w, acc.w);
    }
    atomicAdd(&ctx[b * EH2 + e4 + 0], acc.x);
    atomicAdd(&ctx[b * EH2 + e4 + 1], acc.y);
    atomicAdd(&ctx[b * EH2 + e4 + 2], acc.z);
    atomicAdd(&ctx[b * EH2 + e4 + 3], acc.w);
}

// ---------------------------------------------------------------------------
extern "C" void kernel_launch(void* const* d_in, const int* in_sizes, int n_in,
                              void* d_out, int out_size, void* d_ws, size_t ws_size,
                              hipStream_t stream) {
    const float* enc    = (const float*)d_in[0];   // (B,S,EH2)
    const float* dec    = (const float*)d_in[1];   // (B,DH)
    const int*   mask   = (const int*)  d_in[2];   // (B,S)
    const float* W      = (const float*)d_in[3];   // (EH2+DH, A)
    const float* b_attn = (const float*)d_in[4];   // (A,)
    const float* v      = (const float*)d_in[5];   // (A,)

    float* out = (float*)d_out;
    float* ctx = out;                // B*EH2
    float* wts = out + BB * EH2;     // B*S

    unsigned short* Wt  = (unsigned short*)d_ws;                    // 1 MiB
    float* dec_proj     = (float*)((char*)d_ws + (1 << 20));        // 256 KiB
    float* scores       = dec_proj + BB * AD;                       // 512 KiB

    hipMemsetAsync(ctx, 0, (size_t)BB * EH2 * sizeof(float), stream);

    k0_wprep<<<256, 256, 0, stream>>>(W, Wt);

    k1_decproj<<<BB, 256, 0, stream>>>(dec, W + (size_t)EH2 * AD, b_attn, dec_proj);

    k2_gemm_score<<<MTOT / BM2, 256, 0, stream>>>(enc, Wt, dec_proj, v, scores);

    k3_softmax<<<BB, 256, 0, stream>>>(scores, mask, wts);

    dim3 g4(BB, SS / SCHUNK);        // (128, 8)
    k4_context<<<g4, 256, 0, stream>>>(enc, wts, ctx);
}